// Round 9
// baseline (569.586 us; speedup 1.0000x reference)
//
#include <hip/hip_runtime.h>
#include <hip/hip_cooperative_groups.h>
#include <stdint.h>

namespace cg = cooperative_groups;

#define N_NODES 100000
#define N_EDGES 1600000
#define NF 128
#define NG 512
#define NC 10

#define NBUCK ((N_NODES + 255) / 256)  // 391 buckets of 256 nodes
#define EPB 4096                       // edges per block in bucket passes

#define KSTRIDE 136                    // shorts per LDS B row (128 k-half + 8 pad) = 272 B
#define GEMM_B ((N_NODES + 63) / 64)   // 1563 blocks, 64 rows each

#define CVT_B 6250                     // cvt blocks
#define BT_B 384                       // build_bt blocks
#define BOUNDS_B 3                     // bounds blocks
#define COUNT_B ((N_EDGES + EPB - 1) / EPB)  // 391 edge-chunk blocks (== NBUCK)

typedef short short8 __attribute__((ext_vector_type(8)));
typedef float f32x4 __attribute__((ext_vector_type(4)));

__device__ __forceinline__ unsigned short f2b(float f) {
    unsigned u = __float_as_uint(f);
    u += 0x7fffu + ((u >> 16) & 1u);
    return (unsigned short)(u >> 16);
}
// packed f32->bf16 pair with RNE rounding: dst.lo = bf16(lo), dst.hi = bf16(hi)
__device__ __forceinline__ unsigned cvt2(float lo, float hi) {
    unsigned r;
    asm("v_cvt_pk_bf16_f32 %0, %1, %2" : "=v"(r) : "v"(lo), "v"(hi));
    return r;
}
__device__ __forceinline__ float lo16(unsigned v) { return __uint_as_float(v << 16); }
__device__ __forceinline__ float hi16(unsigned v) { return __uint_as_float(v & 0xffff0000u); }

// ---------------- prep: cvt (x->bf16) + build_bt + bounds + bucket_count, merged ----------------
__global__ __launch_bounds__(256) void prep_kernel(const float* __restrict__ x, unsigned short* __restrict__ xb,
                                                   const float* __restrict__ w1l, const float* __restrict__ w1r,
                                                   const float* __restrict__ w2l, const float* __restrict__ w2r,
                                                   const float* __restrict__ w3l, const float* __restrict__ w3r,
                                                   unsigned short* __restrict__ Bt,
                                                   const int* __restrict__ batch, int* __restrict__ gstart,
                                                   const int* __restrict__ dst, int* __restrict__ bcount) {
    const int b = blockIdx.x, t = threadIdx.x;
    if (b < CVT_B) {
        int i = b * 256 + t;
        const float4* ip = (const float4*)x;
        float4 a = ip[2 * i], c = ip[2 * i + 1];
        uint4 o;
        o.x = cvt2(a.x, a.y);
        o.y = cvt2(a.z, a.w);
        o.z = cvt2(c.x, c.y);
        o.w = cvt2(c.z, c.w);
        ((uint4*)xb)[i] = o;
    } else if (b < CVT_B + BT_B) {
        int i = (b - CVT_B) * 256 + t;
        int layer = i / (128 * 256);
        int r = i % (128 * 256);
        int n = r / 256, k = r % 256;
        const float* wl = (layer == 0) ? w1l : (layer == 1) ? w2l : w3l;
        const float* wr = (layer == 0) ? w1r : (layer == 1) ? w2r : w3r;
        float v = (k < 128) ? wl[k * 128 + n] : wr[(k - 128) * 128 + n];
        Bt[i] = f2b(v);
    } else if (b < CVT_B + BT_B + BOUNDS_B) {
        int g = (b - CVT_B - BT_B) * 256 + t;
        if (g > NG) return;
        int lo = 0, hi = N_NODES;
        while (lo < hi) {
            int mid = (lo + hi) >> 1;
            if (batch[mid] < g) lo = mid + 1; else hi = mid;
        }
        gstart[g] = lo;
    } else {
        __shared__ int h[NBUCK];
        for (int i = t; i < NBUCK; i += 256) h[i] = 0;
        __syncthreads();
        const int base = (b - CVT_B - BT_B - BOUNDS_B) * EPB;
        const int lim = min(base + EPB, N_EDGES);
        for (int i = base + t; i < lim; i += 256) atomicAdd(&h[dst[i] >> 8], 1);
        __syncthreads();
        for (int i = t; i < NBUCK; i += 256)
            if (h[i]) atomicAdd(&bcount[i], h[i]);
    }
}

// ---------------- CSR build: one cooperative kernel (scan | scatter | fill, R6 bodies) ----------------
// 391 blocks x 256 threads, co-resident. Phase 1: block 0 scans bcount -> bbase/gcursor
// (ping-pong Hillis-Steele over 512 slots). grid.sync. Phase 2: block b = edge chunk b
// (EPB 4096), exact R6 bucket_scatter body. grid.sync. Phase 3: block b = bucket b,
// exact R6 bucket_fill body. Removes 2 kernel boundaries + the 1-block scan's
// device-wide idle.
__global__ __launch_bounds__(256) void csr_kernel(const int* __restrict__ src, const int* __restrict__ dst,
                                                  const int* __restrict__ bcount, int* __restrict__ bbase,
                                                  int* __restrict__ gcursor, int* __restrict__ rowptr,
                                                  unsigned* __restrict__ brec, int* __restrict__ eidx) {
    cg::grid_group grid = cg::this_grid();
    __shared__ int sA[512];
    __shared__ int sB[512];
    const int b = blockIdx.x, t = threadIdx.x;

    // phase 1: exclusive scan of bcount (block 0 only)
    if (b == 0) {
        sA[t] = (t < NBUCK) ? bcount[t] : 0;
        sA[t + 256] = (t + 256 < NBUCK) ? bcount[t + 256] : 0;
        __syncthreads();
        int* pin = sA;
        int* pout = sB;
        for (int off = 1; off < 512; off <<= 1) {
            for (int j = t; j < 512; j += 256)
                pout[j] = pin[j] + (j >= off ? pin[j - off] : 0);
            __syncthreads();
            int* tmp = pin; pin = pout; pout = tmp;
        }
        for (int j = t; j < NBUCK; j += 256) {
            int e = pin[j] - bcount[j];
            bbase[j] = e;
            gcursor[j] = e;
        }
        if (t == 0) { bbase[NBUCK] = N_EDGES; rowptr[N_NODES] = N_EDGES; }
    }
    grid.sync();

    // phase 2: scatter (block b = edge chunk b) — R6 body
    {
        for (int i = t; i < NBUCK; i += 256) sA[i] = 0;
        __syncthreads();
        const int base = b * EPB;
        const int lim = min(base + EPB, N_EDGES);
        for (int i = base + t; i < lim; i += 256) atomicAdd(&sA[dst[i] >> 8], 1);
        __syncthreads();
        for (int i = t; i < NBUCK; i += 256) {
            int c = sA[i];
            if (c) sA[i] = atomicAdd(&gcursor[i], c);
        }
        __syncthreads();
        for (int i = base + t; i < lim; i += 256) {
            int d = dst[i];
            int pos = atomicAdd(&sA[d >> 8], 1);
            brec[pos] = ((unsigned)(d & 255) << 17) | (unsigned)src[i];
        }
    }
    grid.sync();

    // phase 3: fill (block b = bucket b) — R6 body
    {
        const int beg = bbase[b], end = bbase[b + 1];
        sA[t] = 0;
        __syncthreads();
        for (int i = beg + t; i < end; i += 256) atomicAdd(&sA[brec[i] >> 17], 1);
        __syncthreads();
        int cnt = sA[t];
        sB[t] = cnt;
        __syncthreads();
        for (int off = 1; off < 256; off <<= 1) {
            int u = (t >= off) ? sB[t - off] : 0;
            __syncthreads();
            sB[t] += u;
            __syncthreads();
        }
        int excl = sB[t] - cnt;
        int node = b * 256 + t;
        if (node < N_NODES) rowptr[node] = beg + excl;
        sA[t] = beg + excl;
        __syncthreads();
        for (int i = beg + t; i < end; i += 256) {
            unsigned r = brec[i];
            int pos = atomicAdd(&sA[r >> 17], 1);
            eidx[pos] = (int)(r & 0x1FFFFu);
        }
    }
}

// ---------------- mean aggregation: one wave per node (R2-proven, fabric-floor ~56us) ----------------
__global__ __launch_bounds__(256) void agg_kernel(const unsigned short* __restrict__ F,
                                                  const int* __restrict__ rowptr,
                                                  const int* __restrict__ eidx,
                                                  unsigned short* __restrict__ M) {
    int node = blockIdx.x * 4 + (threadIdx.x >> 6);
    if (node >= N_NODES) return;
    const int lane = threadIdx.x & 63;
    const int quad = lane >> 4, ql = lane & 15;
    const int beg = rowptr[node], end = rowptr[node + 1];
    const char* Fb = (const char*)F;
    const unsigned qoff = (unsigned)ql << 4;  // byte offset of this lane's 16B segment

    float a0 = 0.f, a1 = 0.f, a2 = 0.f, a3 = 0.f, a4 = 0.f, a5 = 0.f, a6 = 0.f, a7 = 0.f;

    for (int cs = beg; cs < end; cs += 64) {
        int e = cs + lane;
        int idx = eidx[e < end ? e : end - 1];  // one coalesced 64-wide index load
        int n = end - cs;
        if (n > 64) n = 64;
        const int nfull = n >> 4;  // full 16-edge groups (uniform across wave)
        int l = quad;
        for (int g = 0; g < nfull; ++g, l += 16) {
            int r0 = __shfl(idx, l);
            int r1 = __shfl(idx, l + 4);
            int r2 = __shfl(idx, l + 8);
            int r3 = __shfl(idx, l + 12);
            uint4 v0 = *(const uint4*)(Fb + (((unsigned)r0 << 8) | qoff));
            uint4 v1 = *(const uint4*)(Fb + (((unsigned)r1 << 8) | qoff));
            uint4 v2 = *(const uint4*)(Fb + (((unsigned)r2 << 8) | qoff));
            uint4 v3 = *(const uint4*)(Fb + (((unsigned)r3 << 8) | qoff));
            a0 += lo16(v0.x) + lo16(v1.x) + lo16(v2.x) + lo16(v3.x);
            a1 += hi16(v0.x) + hi16(v1.x) + hi16(v2.x) + hi16(v3.x);
            a2 += lo16(v0.y) + lo16(v1.y) + lo16(v2.y) + lo16(v3.y);
            a3 += hi16(v0.y) + hi16(v1.y) + hi16(v2.y) + hi16(v3.y);
            a4 += lo16(v0.z) + lo16(v1.z) + lo16(v2.z) + lo16(v3.z);
            a5 += hi16(v0.z) + hi16(v1.z) + hi16(v2.z) + hi16(v3.z);
            a6 += lo16(v0.w) + lo16(v1.w) + lo16(v2.w) + lo16(v3.w);
            a7 += hi16(v0.w) + hi16(v1.w) + hi16(v2.w) + hi16(v3.w);
        }
        const int base = nfull << 4;
        // uniform masked-4 tail: ceil(rem/4) iterations, shfl outside any branch
        for (int it = base; it < n; it += 4) {
            int l0 = it + quad;
            int r0 = __shfl(idx, l0 < n ? l0 : n - 1);
            float s0 = (l0 < n) ? 1.f : 0.f;
            uint4 v0 = *(const uint4*)(Fb + (((unsigned)r0 << 8) | qoff));
            a0 += s0 * lo16(v0.x); a1 += s0 * hi16(v0.x);
            a2 += s0 * lo16(v0.y); a3 += s0 * hi16(v0.y);
            a4 += s0 * lo16(v0.z); a5 += s0 * hi16(v0.z);
            a6 += s0 * lo16(v0.w); a7 += s0 * hi16(v0.w);
        }
    }

    a0 += __shfl_xor(a0, 16); a0 += __shfl_xor(a0, 32);
    a1 += __shfl_xor(a1, 16); a1 += __shfl_xor(a1, 32);
    a2 += __shfl_xor(a2, 16); a2 += __shfl_xor(a2, 32);
    a3 += __shfl_xor(a3, 16); a3 += __shfl_xor(a3, 32);
    a4 += __shfl_xor(a4, 16); a4 += __shfl_xor(a4, 32);
    a5 += __shfl_xor(a5, 16); a5 += __shfl_xor(a5, 32);
    a6 += __shfl_xor(a6, 16); a6 += __shfl_xor(a6, 32);
    a7 += __shfl_xor(a7, 16); a7 += __shfl_xor(a7, 32);

    if (quad == 0) {
        float inv = 1.0f / (float)max(end - beg, 1);
        uint4 o;
        o.x = cvt2(a0 * inv, a1 * inv);
        o.y = cvt2(a2 * inv, a3 * inv);
        o.z = cvt2(a4 * inv, a5 * inv);
        o.w = cvt2(a6 * inv, a7 * inv);
        ((uint4*)M)[(size_t)node * 16 + ql] = o;
    }
}

// ---------------- GEMM: H = relu([mean|feat] @ Bt^T + b), optional fused gate ----------------
// R9: R6 LDS-staged form (proven ~25us) + A-loads hoisted into registers before the
// staging loop so HBM latency hides under B-staging/barriers. MFMA operand order
// identical -> bitwise-identical output. 64 rows/block, 1563 blocks, 4 blocks/CU.
__global__ __launch_bounds__(256, 4) void gemm_kernel(const unsigned short* __restrict__ Am,
                                                      const unsigned short* __restrict__ Ax,
                                                      const unsigned short* __restrict__ Bt,
                                                      const float* __restrict__ bias,
                                                      unsigned short* __restrict__ Out,
                                                      const float* __restrict__ gatew,
                                                      const float* __restrict__ gateb,
                                                      float* __restrict__ gate) {
    const int t = threadIdx.x;
    const int wave = t >> 6, lane = t & 63;
    const int lrow = lane & 15, quad = lane >> 4;
    const int wrow0 = blockIdx.x * 64 + wave * 16;

    __shared__ __attribute__((aligned(16))) unsigned short Bs[128 * KSTRIDE];  // 34.8 KB

    f32x4 acc[8];
#pragma unroll
    for (int j = 0; j < 8; ++j) acc[j] = (f32x4){0.f, 0.f, 0.f, 0.f};

    int arow = wrow0 + lrow;
    if (arow > N_NODES - 1) arow = N_NODES - 1;

    // hoisted A fragments (issue before staging; latency hides under stage+barrier)
    short8 afm[4], afx[4];
#pragma unroll
    for (int c = 0; c < 4; ++c) {
        const int kb = c * 32 + quad * 8;
        afm[c] = *(const short8*)(Am + (size_t)arow * 128 + kb);
        afx[c] = *(const short8*)(Ax + (size_t)arow * 128 + kb);
    }

#pragma unroll
    for (int p = 0; p < 2; ++p) {
        if (p) __syncthreads();  // all waves done reading pass-0 Bs
        // stage k-half p: 128 rows x 16 uint4 = 2048 units, 8 per thread
#pragma unroll
        for (int i = 0; i < 8; ++i) {
            int u = t + i * 256;
            int r = u >> 4, seg = u & 15;
            *(uint4*)(Bs + r * KSTRIDE + seg * 8) =
                *(const uint4*)(Bt + (size_t)r * 256 + p * 128 + seg * 8);
        }
        __syncthreads();

#pragma unroll
        for (int c = 0; c < 4; ++c) {
            const int kb = c * 32 + quad * 8;
            short8 af = p ? afx[c] : afm[c];
#pragma unroll
            for (int nt = 0; nt < 8; ++nt) {
                short8 bf = *(const short8*)(Bs + (nt * 16 + lrow) * KSTRIDE + kb);
                acc[nt] = __builtin_amdgcn_mfma_f32_16x16x32_bf16(af, bf, acc[nt], 0, 0, 0);
            }
        }
    }

    float gpart[4] = {0.f, 0.f, 0.f, 0.f};
    const int rbase = wrow0 + quad * 4;

#pragma unroll
    for (int nt = 0; nt < 8; ++nt) {
        int col = nt * 16 + lrow;
        float bc = bias[col];
        float gw = gatew ? gatew[col] : 0.f;
#pragma unroll
        for (int r = 0; r < 4; ++r) {
            int row = rbase + r;
            float v = fmaxf(acc[nt][r] + bc, 0.f);
            if (row < N_NODES) gpart[r] += v * gw;
            // pack col-pair: even lrow stores 4 bytes covering (col, col+1)
            unsigned sv = (unsigned)f2b(v);
            unsigned nb = (unsigned)__shfl_xor((int)sv, 1);
            if (((lrow & 1) == 0) && row < N_NODES)
                *(unsigned*)(Out + (size_t)row * 128 + col) = sv | (nb << 16);
        }
    }
    if (gatew) {
        float gb = gateb[0];
#pragma unroll
        for (int r = 0; r < 4; ++r) {
            float g = gpart[r];
            g += __shfl_xor(g, 1);
            g += __shfl_xor(g, 2);
            g += __shfl_xor(g, 4);
            g += __shfl_xor(g, 8);
            if (lrow == 0) {
                int row = rbase + r;
                if (row < N_NODES) gate[row] = g + gb;
            }
        }
    }
}

// ---------------- fused attention-pool + MLP + log_softmax: 4 waves per graph ----------------
__global__ __launch_bounds__(256) void pool_mlp_kernel(const unsigned short* __restrict__ h,
                                                       const float* __restrict__ gate,
                                                       const int* __restrict__ gstart,
                                                       const float* __restrict__ l1w,
                                                       const float* __restrict__ l1b,
                                                       const float* __restrict__ l2w,
                                                       const float* __restrict__ l2b,
                                                       float* __restrict__ out) {
    const int g = blockIdx.x;
    const int t = threadIdx.x;
    const int w = t >> 6, lane = t & 63;
    __shared__ float mred[4];
    __shared__ float sred[4];
    __shared__ float pax[4][128];
    __shared__ float pooled_s[128];
    __shared__ float hid_s[128];

    const int beg = gstart[g], end = gstart[g + 1];

    // pass 1: segment max of gate
    float m = -INFINITY;
    for (int i = beg + t; i < end; i += 256) m = fmaxf(m, gate[i]);
#pragma unroll
    for (int o = 32; o; o >>= 1) m = fmaxf(m, __shfl_xor(m, o));
    if (lane == 0) mred[w] = m;
    __syncthreads();
    m = fmaxf(fmaxf(mred[0], mred[1]), fmaxf(mred[2], mred[3]));

    // pass 2: e-sum + unnormalized weighted feature sum (one expf per node)
    float s = 0.f, ax = 0.f, ay = 0.f;
    const unsigned* hb = (const unsigned*)h;
    for (int i = beg + w; i < end; i += 4) {
        float e = expf(gate[i] - m);  // wave-uniform
        unsigned v = hb[(size_t)i * 64 + lane];
        s += e;
        ax += e * lo16(v);
        ay += e * hi16(v);
    }
    if (lane == 0) sred[w] = s;
    pax[w][2 * lane] = ax;
    pax[w][2 * lane + 1] = ay;
    __syncthreads();

    if (t < 128) {
        float ssum = sred[0] + sred[1] + sred[2] + sred[3];
        float invs = (ssum > 0.f) ? 1.0f / ssum : 0.f;
        pooled_s[t] = (pax[0][t] + pax[1][t] + pax[2][t] + pax[3][t]) * invs;
    }
    __syncthreads();

    // MLP layer 1: waves 0,1 compute 64 outputs each
    if (w < 2) {
        const int o = w * 64 + lane;
        float acc = l1b[o];
        for (int k = 0; k < 128; ++k) acc += pooled_s[k] * l1w[k * 128 + o];
        hid_s[o] = fmaxf(acc, 0.f);
    }
    __syncthreads();

    if (w == 0) {
        float o10 = 0.f;
        if (lane < NC) {
            o10 = l2b[lane];
            for (int k = 0; k < 128; ++k) o10 += hid_s[k] * l2w[k * NC + lane];
        }
        float mm = -INFINITY;
#pragma unroll
        for (int j = 0; j < NC; ++j) mm = fmaxf(mm, __shfl(o10, j));
        float ss = 0.f;
#pragma unroll
        for (int j = 0; j < NC; ++j) ss += expf(__shfl(o10, j) - mm);
        float lse = mm + logf(ss);
        if (lane < NC) out[g * NC + lane] = o10 - lse;
    }
}

extern "C" void kernel_launch(void* const* d_in, const int* in_sizes, int n_in,
                              void* d_out, int out_size, void* d_ws, size_t ws_size,
                              hipStream_t stream) {
    const float* x   = (const float*)d_in[0];
    const int* ei    = (const int*)d_in[1];
    const int* batch = (const int*)d_in[2];
    const float* w1l = (const float*)d_in[3];
    const float* b1  = (const float*)d_in[4];
    const float* w1r = (const float*)d_in[5];
    const float* w2l = (const float*)d_in[6];
    const float* b2  = (const float*)d_in[7];
    const float* w2r = (const float*)d_in[8];
    const float* w3l = (const float*)d_in[9];
    const float* b3  = (const float*)d_in[10];
    const float* w3r = (const float*)d_in[11];
    const float* gw  = (const float*)d_in[12];
    const float* gb  = (const float*)d_in[13];
    const float* l1w = (const float*)d_in[14];
    const float* l1b = (const float*)d_in[15];
    const float* l2w = (const float*)d_in[16];
    const float* l2b = (const float*)d_in[17];
    float* out = (float*)d_out;

    const int* src = ei;
    const int* dst = ei + N_EDGES;

    char* base = (char*)d_ws;
    size_t off = 0;
    auto carve = [&](size_t bytes) -> void* {
        void* r = base + off;
        off = (off + bytes + 255) & ~(size_t)255;
        return r;
    };
    int* rowptr         = (int*)carve((size_t)(N_NODES + 1) * 4);
    int* eidx           = (int*)carve((size_t)N_EDGES * 4);
    unsigned short* Bt  = (unsigned short*)carve((size_t)3 * 128 * 256 * 2);
    unsigned short* xb  = (unsigned short*)carve((size_t)N_NODES * NF * 2);
    unsigned short* mn  = (unsigned short*)carve((size_t)N_NODES * NF * 2);
    unsigned short* hA  = (unsigned short*)carve((size_t)N_NODES * NF * 2);
    unsigned short* hB  = (unsigned short*)carve((size_t)N_NODES * NF * 2);
    float* gate         = (float*)carve((size_t)N_NODES * 4);
    int* gstart         = (int*)carve(513 * 4);
    int* bcount         = (int*)carve((NBUCK + 1) * 4);
    int* bbase          = (int*)carve((NBUCK + 1) * 4);
    int* gcursor        = (int*)carve((NBUCK + 1) * 4);
    unsigned* brec      = (unsigned*)mn;  // alias: mn is dead until the first agg_kernel

    hipMemsetAsync(bcount, 0, (size_t)NBUCK * 4, stream);

    prep_kernel<<<CVT_B + BT_B + BOUNDS_B + COUNT_B, 256, 0, stream>>>(
        x, xb, w1l, w1r, w2l, w2r, w3l, w3r, Bt, batch, gstart, dst, bcount);

    {
        void* cargs[] = {(void*)&src, (void*)&dst, (void*)&bcount, (void*)&bbase,
                         (void*)&gcursor, (void*)&rowptr, (void*)&brec, (void*)&eidx};
        hipLaunchCooperativeKernel((const void*)csr_kernel, dim3(COUNT_B), dim3(256),
                                   cargs, 0, stream);
    }

    const int AGG_B = (N_NODES + 3) / 4;  // 25000

    agg_kernel<<<AGG_B, 256, 0, stream>>>(xb, rowptr, eidx, mn);
    gemm_kernel<<<GEMM_B, 256, 0, stream>>>(mn, xb, Bt, b1, hA, nullptr, nullptr, nullptr);
    agg_kernel<<<AGG_B, 256, 0, stream>>>(hA, rowptr, eidx, mn);
    gemm_kernel<<<GEMM_B, 256, 0, stream>>>(mn, hA, Bt + 32768, b2, hB, nullptr, nullptr, nullptr);
    agg_kernel<<<AGG_B, 256, 0, stream>>>(hB, rowptr, eidx, mn);
    gemm_kernel<<<GEMM_B, 256, 0, stream>>>(mn, hB, Bt + 65536, b3, hA, gw, gb, gate);

    pool_mlp_kernel<<<NG, 256, 0, stream>>>(hA, gate, gstart, l1w, l1b, l2w, l2b, out);
}

// Round 10
// 439.368 us; speedup vs baseline: 1.2964x; 1.2964x over previous
//
#include <hip/hip_runtime.h>
#include <stdint.h>

#define N_NODES 100000
#define N_EDGES 1600000
#define NF 128
#define NG 512
#define NC 10

#define NBUCK ((N_NODES + 255) / 256)  // 391 buckets of 256 nodes
#define EPB 4096                       // edges per block in bucket passes

#define KSTRIDE 136                    // shorts per LDS B row (128 k-half + 8 pad) = 272 B
#define GEMM_B ((N_NODES + 63) / 64)   // 1563 blocks, 64 rows each

#define CVT_B 6250                     // cvt blocks
#define BT_B 384                       // build_bt blocks
#define BOUNDS_B 3                     // bounds blocks
#define COUNT_B ((N_EDGES + EPB - 1) / EPB)  // 391 bucket-count blocks

typedef short short8 __attribute__((ext_vector_type(8)));
typedef float f32x4 __attribute__((ext_vector_type(4)));

__device__ __forceinline__ unsigned short f2b(float f) {
    unsigned u = __float_as_uint(f);
    u += 0x7fffu + ((u >> 16) & 1u);
    return (unsigned short)(u >> 16);
}
// packed f32->bf16 pair with RNE rounding: dst.lo = bf16(lo), dst.hi = bf16(hi)
__device__ __forceinline__ unsigned cvt2(float lo, float hi) {
    unsigned r;
    asm("v_cvt_pk_bf16_f32 %0, %1, %2" : "=v"(r) : "v"(lo), "v"(hi));
    return r;
}
__device__ __forceinline__ float lo16(unsigned v) { return __uint_as_float(v << 16); }
__device__ __forceinline__ float hi16(unsigned v) { return __uint_as_float(v & 0xffff0000u); }

// ---------------- prep: cvt (x->bf16) + build_bt + bounds + bucket_count, merged ----------------
__global__ __launch_bounds__(256) void prep_kernel(const float* __restrict__ x, unsigned short* __restrict__ xb,
                                                   const float* __restrict__ w1l, const float* __restrict__ w1r,
                                                   const float* __restrict__ w2l, const float* __restrict__ w2r,
                                                   const float* __restrict__ w3l, const float* __restrict__ w3r,
                                                   unsigned short* __restrict__ Bt,
                                                   const int* __restrict__ batch, int* __restrict__ gstart,
                                                   const int* __restrict__ dst, int* __restrict__ bcount) {
    const int b = blockIdx.x, t = threadIdx.x;
    if (b < CVT_B) {
        int i = b * 256 + t;
        const float4* ip = (const float4*)x;
        float4 a = ip[2 * i], c = ip[2 * i + 1];
        uint4 o;
        o.x = cvt2(a.x, a.y);
        o.y = cvt2(a.z, a.w);
        o.z = cvt2(c.x, c.y);
        o.w = cvt2(c.z, c.w);
        ((uint4*)xb)[i] = o;
    } else if (b < CVT_B + BT_B) {
        int i = (b - CVT_B) * 256 + t;
        int layer = i / (128 * 256);
        int r = i % (128 * 256);
        int n = r / 256, k = r % 256;
        const float* wl = (layer == 0) ? w1l : (layer == 1) ? w2l : w3l;
        const float* wr = (layer == 0) ? w1r : (layer == 1) ? w2r : w3r;
        float v = (k < 128) ? wl[k * 128 + n] : wr[(k - 128) * 128 + n];
        Bt[i] = f2b(v);
    } else if (b < CVT_B + BT_B + BOUNDS_B) {
        int g = (b - CVT_B - BT_B) * 256 + t;
        if (g > NG) return;
        int lo = 0, hi = N_NODES;
        while (lo < hi) {
            int mid = (lo + hi) >> 1;
            if (batch[mid] < g) lo = mid + 1; else hi = mid;
        }
        gstart[g] = lo;
    } else {
        __shared__ int h[NBUCK];
        for (int i = t; i < NBUCK; i += 256) h[i] = 0;
        __syncthreads();
        const int base = (b - CVT_B - BT_B - BOUNDS_B) * EPB;
        const int lim = min(base + EPB, N_EDGES);
        for (int i = base + t; i < lim; i += 256) atomicAdd(&h[dst[i] >> 8], 1);
        __syncthreads();
        for (int i = t; i < NBUCK; i += 256)
            if (h[i]) atomicAdd(&bcount[i], h[i]);
    }
}

// ---------------- CSR build (scan / scatter / fill) — R6-proven form ----------------
__global__ __launch_bounds__(512) void bucket_scan(const int* __restrict__ bcount, int* __restrict__ bbase,
                                                   int* __restrict__ gcursor, int* __restrict__ rowptr) {
    __shared__ int sh[512];
    const int t = threadIdx.x;
    int v = (t < NBUCK) ? bcount[t] : 0;
    sh[t] = v;
    __syncthreads();
    for (int off = 1; off < 512; off <<= 1) {
        int u = (t >= off) ? sh[t - off] : 0;
        __syncthreads();
        sh[t] += u;
        __syncthreads();
    }
    if (t < NBUCK) {
        int e = sh[t] - v;
        bbase[t] = e;
        gcursor[t] = e;
    }
    if (t == NBUCK - 1) bbase[NBUCK] = sh[t];
    if (t == 0) rowptr[N_NODES] = N_EDGES;
}

__global__ __launch_bounds__(256) void bucket_scatter(const int* __restrict__ src, const int* __restrict__ dst,
                                                      int* __restrict__ gcursor, unsigned* __restrict__ brec) {
    __shared__ int h[NBUCK];
    for (int i = threadIdx.x; i < NBUCK; i += 256) h[i] = 0;
    __syncthreads();
    const int base = blockIdx.x * EPB;
    const int lim = min(base + EPB, N_EDGES);
    for (int i = base + threadIdx.x; i < lim; i += 256) atomicAdd(&h[dst[i] >> 8], 1);
    __syncthreads();
    for (int i = threadIdx.x; i < NBUCK; i += 256) {
        int c = h[i];
        if (c) h[i] = atomicAdd(&gcursor[i], c);
    }
    __syncthreads();
    for (int i = base + threadIdx.x; i < lim; i += 256) {
        int d = dst[i];
        int pos = atomicAdd(&h[d >> 8], 1);
        brec[pos] = ((unsigned)(d & 255) << 17) | (unsigned)src[i];
    }
}

__global__ __launch_bounds__(256) void bucket_fill(const unsigned* __restrict__ brec, const int* __restrict__ bbase,
                                                   int* __restrict__ rowptr, int* __restrict__ eidx) {
    __shared__ int nh[256];
    __shared__ int sc[256];
    const int b = blockIdx.x, t = threadIdx.x;
    const int beg = bbase[b], end = bbase[b + 1];
    nh[t] = 0;
    __syncthreads();
    for (int i = beg + t; i < end; i += 256) atomicAdd(&nh[brec[i] >> 17], 1);
    __syncthreads();
    int cnt = nh[t];
    sc[t] = cnt;
    __syncthreads();
    for (int off = 1; off < 256; off <<= 1) {
        int u = (t >= off) ? sc[t - off] : 0;
        __syncthreads();
        sc[t] += u;
        __syncthreads();
    }
    int excl = sc[t] - cnt;
    int node = b * 256 + t;
    if (node < N_NODES) rowptr[node] = beg + excl;
    nh[t] = beg + excl;
    __syncthreads();
    for (int i = beg + t; i < end; i += 256) {
        unsigned r = brec[i];
        int pos = atomicAdd(&nh[r >> 17], 1);
        eidx[pos] = (int)(r & 0x1FFFFu);
    }
}

// ---------------- mean aggregation: one wave per node (R2-proven, fabric-floor ~56us) ----------------
__global__ __launch_bounds__(256) void agg_kernel(const unsigned short* __restrict__ F,
                                                  const int* __restrict__ rowptr,
                                                  const int* __restrict__ eidx,
                                                  unsigned short* __restrict__ M) {
    int node = blockIdx.x * 4 + (threadIdx.x >> 6);
    if (node >= N_NODES) return;
    const int lane = threadIdx.x & 63;
    const int quad = lane >> 4, ql = lane & 15;
    const int beg = rowptr[node], end = rowptr[node + 1];
    const char* Fb = (const char*)F;
    const unsigned qoff = (unsigned)ql << 4;  // byte offset of this lane's 16B segment

    float a0 = 0.f, a1 = 0.f, a2 = 0.f, a3 = 0.f, a4 = 0.f, a5 = 0.f, a6 = 0.f, a7 = 0.f;

    for (int cs = beg; cs < end; cs += 64) {
        int e = cs + lane;
        int idx = eidx[e < end ? e : end - 1];  // one coalesced 64-wide index load
        int n = end - cs;
        if (n > 64) n = 64;
        const int nfull = n >> 4;  // full 16-edge groups (uniform across wave)
        int l = quad;
        for (int g = 0; g < nfull; ++g, l += 16) {
            int r0 = __shfl(idx, l);
            int r1 = __shfl(idx, l + 4);
            int r2 = __shfl(idx, l + 8);
            int r3 = __shfl(idx, l + 12);
            uint4 v0 = *(const uint4*)(Fb + (((unsigned)r0 << 8) | qoff));
            uint4 v1 = *(const uint4*)(Fb + (((unsigned)r1 << 8) | qoff));
            uint4 v2 = *(const uint4*)(Fb + (((unsigned)r2 << 8) | qoff));
            uint4 v3 = *(const uint4*)(Fb + (((unsigned)r3 << 8) | qoff));
            a0 += lo16(v0.x) + lo16(v1.x) + lo16(v2.x) + lo16(v3.x);
            a1 += hi16(v0.x) + hi16(v1.x) + hi16(v2.x) + hi16(v3.x);
            a2 += lo16(v0.y) + lo16(v1.y) + lo16(v2.y) + lo16(v3.y);
            a3 += hi16(v0.y) + hi16(v1.y) + hi16(v2.y) + hi16(v3.y);
            a4 += lo16(v0.z) + lo16(v1.z) + lo16(v2.z) + lo16(v3.z);
            a5 += hi16(v0.z) + hi16(v1.z) + hi16(v2.z) + hi16(v3.z);
            a6 += lo16(v0.w) + lo16(v1.w) + lo16(v2.w) + lo16(v3.w);
            a7 += hi16(v0.w) + hi16(v1.w) + hi16(v2.w) + hi16(v3.w);
        }
        const int base = nfull << 4;
        // uniform masked-4 tail: ceil(rem/4) iterations, shfl outside any branch
        for (int it = base; it < n; it += 4) {
            int l0 = it + quad;
            int r0 = __shfl(idx, l0 < n ? l0 : n - 1);
            float s0 = (l0 < n) ? 1.f : 0.f;
            uint4 v0 = *(const uint4*)(Fb + (((unsigned)r0 << 8) | qoff));
            a0 += s0 * lo16(v0.x); a1 += s0 * hi16(v0.x);
            a2 += s0 * lo16(v0.y); a3 += s0 * hi16(v0.y);
            a4 += s0 * lo16(v0.z); a5 += s0 * hi16(v0.z);
            a6 += s0 * lo16(v0.w); a7 += s0 * hi16(v0.w);
        }
    }

    a0 += __shfl_xor(a0, 16); a0 += __shfl_xor(a0, 32);
    a1 += __shfl_xor(a1, 16); a1 += __shfl_xor(a1, 32);
    a2 += __shfl_xor(a2, 16); a2 += __shfl_xor(a2, 32);
    a3 += __shfl_xor(a3, 16); a3 += __shfl_xor(a3, 32);
    a4 += __shfl_xor(a4, 16); a4 += __shfl_xor(a4, 32);
    a5 += __shfl_xor(a5, 16); a5 += __shfl_xor(a5, 32);
    a6 += __shfl_xor(a6, 16); a6 += __shfl_xor(a6, 32);
    a7 += __shfl_xor(a7, 16); a7 += __shfl_xor(a7, 32);

    if (quad == 0) {
        float inv = 1.0f / (float)max(end - beg, 1);
        uint4 o;
        o.x = cvt2(a0 * inv, a1 * inv);
        o.y = cvt2(a2 * inv, a3 * inv);
        o.z = cvt2(a4 * inv, a5 * inv);
        o.w = cvt2(a6 * inv, a7 * inv);
        ((uint4*)M)[(size_t)node * 16 + ql] = o;
    }
}

// ---------------- GEMM: H = relu([mean|feat] @ Bt^T + b), optional fused gate ----------------
// 64 rows/block, 1563 blocks; each wave = 1 row-tile x 8 col-tiles.
// K-split LDS: stage 128 B-rows x 128 k-half (34.8 KB) per pass; 4 blocks/CU LDS cap.
__global__ __launch_bounds__(256, 4) void gemm_kernel(const unsigned short* __restrict__ Am,
                                                      const unsigned short* __restrict__ Ax,
                                                      const unsigned short* __restrict__ Bt,
                                                      const float* __restrict__ bias,
                                                      unsigned short* __restrict__ Out,
                                                      const float* __restrict__ gatew,
                                                      const float* __restrict__ gateb,
                                                      float* __restrict__ gate) {
    const int t = threadIdx.x;
    const int wave = t >> 6, lane = t & 63;
    const int lrow = lane & 15, quad = lane >> 4;
    const int wrow0 = blockIdx.x * 64 + wave * 16;

    __shared__ __attribute__((aligned(16))) unsigned short Bs[128 * KSTRIDE];  // 34.8 KB

    f32x4 acc[8];
#pragma unroll
    for (int j = 0; j < 8; ++j) acc[j] = (f32x4){0.f, 0.f, 0.f, 0.f};

    int arow = wrow0 + lrow;
    if (arow > N_NODES - 1) arow = N_NODES - 1;

    for (int p = 0; p < 2; ++p) {
        if (p) __syncthreads();  // all waves done reading pass-0 Bs
        // stage k-half p: 128 rows x 16 uint4 = 2048 units, 8 per thread
#pragma unroll
        for (int i = 0; i < 8; ++i) {
            int u = t + i * 256;
            int r = u >> 4, seg = u & 15;
            *(uint4*)(Bs + r * KSTRIDE + seg * 8) =
                *(const uint4*)(Bt + (size_t)r * 256 + p * 128 + seg * 8);
        }
        __syncthreads();

        const unsigned short* Aarr = p ? Ax : Am;
#pragma unroll
        for (int c = 0; c < 4; ++c) {
            const int kb = c * 32 + quad * 8;
            short8 af = *(const short8*)(Aarr + (size_t)arow * 128 + kb);
#pragma unroll
            for (int nt = 0; nt < 8; ++nt) {
                short8 bf = *(const short8*)(Bs + (nt * 16 + lrow) * KSTRIDE + kb);
                acc[nt] = __builtin_amdgcn_mfma_f32_16x16x32_bf16(af, bf, acc[nt], 0, 0, 0);
            }
        }
    }

    float gpart[4] = {0.f, 0.f, 0.f, 0.f};
    const int rbase = wrow0 + quad * 4;

#pragma unroll
    for (int nt = 0; nt < 8; ++nt) {
        int col = nt * 16 + lrow;
        float bc = bias[col];
        float gw = gatew ? gatew[col] : 0.f;
#pragma unroll
        for (int r = 0; r < 4; ++r) {
            int row = rbase + r;
            float v = fmaxf(acc[nt][r] + bc, 0.f);
            if (row < N_NODES) gpart[r] += v * gw;
            // pack col-pair: even lrow stores 4 bytes covering (col, col+1)
            unsigned sv = (unsigned)f2b(v);
            unsigned nb = (unsigned)__shfl_xor((int)sv, 1);
            if (((lrow & 1) == 0) && row < N_NODES)
                *(unsigned*)(Out + (size_t)row * 128 + col) = sv | (nb << 16);
        }
    }
    if (gatew) {
        float gb = gateb[0];
#pragma unroll
        for (int r = 0; r < 4; ++r) {
            float g = gpart[r];
            g += __shfl_xor(g, 1);
            g += __shfl_xor(g, 2);
            g += __shfl_xor(g, 4);
            g += __shfl_xor(g, 8);
            if (lrow == 0) {
                int row = rbase + r;
                if (row < N_NODES) gate[row] = g + gb;
            }
        }
    }
}

// ---------------- fused attention-pool + MLP + log_softmax: 4 waves per graph ----------------
__global__ __launch_bounds__(256) void pool_mlp_kernel(const unsigned short* __restrict__ h,
                                                       const float* __restrict__ gate,
                                                       const int* __restrict__ gstart,
                                                       const float* __restrict__ l1w,
                                                       const float* __restrict__ l1b,
                                                       const float* __restrict__ l2w,
                                                       const float* __restrict__ l2b,
                                                       float* __restrict__ out) {
    const int g = blockIdx.x;
    const int t = threadIdx.x;
    const int w = t >> 6, lane = t & 63;
    __shared__ float mred[4];
    __shared__ float sred[4];
    __shared__ float pax[4][128];
    __shared__ float pooled_s[128];
    __shared__ float hid_s[128];

    const int beg = gstart[g], end = gstart[g + 1];

    // pass 1: segment max of gate
    float m = -INFINITY;
    for (int i = beg + t; i < end; i += 256) m = fmaxf(m, gate[i]);
#pragma unroll
    for (int o = 32; o; o >>= 1) m = fmaxf(m, __shfl_xor(m, o));
    if (lane == 0) mred[w] = m;
    __syncthreads();
    m = fmaxf(fmaxf(mred[0], mred[1]), fmaxf(mred[2], mred[3]));

    // pass 2: e-sum + unnormalized weighted feature sum (one expf per node)
    float s = 0.f, ax = 0.f, ay = 0.f;
    const unsigned* hb = (const unsigned*)h;
    for (int i = beg + w; i < end; i += 4) {
        float e = expf(gate[i] - m);  // wave-uniform
        unsigned v = hb[(size_t)i * 64 + lane];
        s += e;
        ax += e * lo16(v);
        ay += e * hi16(v);
    }
    if (lane == 0) sred[w] = s;
    pax[w][2 * lane] = ax;
    pax[w][2 * lane + 1] = ay;
    __syncthreads();

    if (t < 128) {
        float ssum = sred[0] + sred[1] + sred[2] + sred[3];
        float invs = (ssum > 0.f) ? 1.0f / ssum : 0.f;
        pooled_s[t] = (pax[0][t] + pax[1][t] + pax[2][t] + pax[3][t]) * invs;
    }
    __syncthreads();

    // MLP layer 1: waves 0,1 compute 64 outputs each
    if (w < 2) {
        const int o = w * 64 + lane;
        float acc = l1b[o];
        for (int k = 0; k < 128; ++k) acc += pooled_s[k] * l1w[k * 128 + o];
        hid_s[o] = fmaxf(acc, 0.f);
    }
    __syncthreads();

    if (w == 0) {
        float o10 = 0.f;
        if (lane < NC) {
            o10 = l2b[lane];
            for (int k = 0; k < 128; ++k) o10 += hid_s[k] * l2w[k * NC + lane];
        }
        float mm = -INFINITY;
#pragma unroll
        for (int j = 0; j < NC; ++j) mm = fmaxf(mm, __shfl(o10, j));
        float ss = 0.f;
#pragma unroll
        for (int j = 0; j < NC; ++j) ss += expf(__shfl(o10, j) - mm);
        float lse = mm + logf(ss);
        if (lane < NC) out[g * NC + lane] = o10 - lse;
    }
}

extern "C" void kernel_launch(void* const* d_in, const int* in_sizes, int n_in,
                              void* d_out, int out_size, void* d_ws, size_t ws_size,
                              hipStream_t stream) {
    const float* x   = (const float*)d_in[0];
    const int* ei    = (const int*)d_in[1];
    const int* batch = (const int*)d_in[2];
    const float* w1l = (const float*)d_in[3];
    const float* b1  = (const float*)d_in[4];
    const float* w1r = (const float*)d_in[5];
    const float* w2l = (const float*)d_in[6];
    const float* b2  = (const float*)d_in[7];
    const float* w2r = (const float*)d_in[8];
    const float* w3l = (const float*)d_in[9];
    const float* b3  = (const float*)d_in[10];
    const float* w3r = (const float*)d_in[11];
    const float* gw  = (const float*)d_in[12];
    const float* gb  = (const float*)d_in[13];
    const float* l1w = (const float*)d_in[14];
    const float* l1b = (const float*)d_in[15];
    const float* l2w = (const float*)d_in[16];
    const float* l2b = (const float*)d_in[17];
    float* out = (float*)d_out;

    const int* src = ei;
    const int* dst = ei + N_EDGES;

    char* base = (char*)d_ws;
    size_t off = 0;
    auto carve = [&](size_t bytes) -> void* {
        void* r = base + off;
        off = (off + bytes + 255) & ~(size_t)255;
        return r;
    };
    int* rowptr         = (int*)carve((size_t)(N_NODES + 1) * 4);
    int* eidx           = (int*)carve((size_t)N_EDGES * 4);
    unsigned short* Bt  = (unsigned short*)carve((size_t)3 * 128 * 256 * 2);
    unsigned short* xb  = (unsigned short*)carve((size_t)N_NODES * NF * 2);
    unsigned short* mn  = (unsigned short*)carve((size_t)N_NODES * NF * 2);
    unsigned short* hA  = (unsigned short*)carve((size_t)N_NODES * NF * 2);
    unsigned short* hB  = (unsigned short*)carve((size_t)N_NODES * NF * 2);
    float* gate         = (float*)carve((size_t)N_NODES * 4);
    int* gstart         = (int*)carve(513 * 4);
    int* bcount         = (int*)carve((NBUCK + 1) * 4);
    int* bbase          = (int*)carve((NBUCK + 1) * 4);
    int* gcursor        = (int*)carve((NBUCK + 1) * 4);
    unsigned* brec      = (unsigned*)mn;  // alias: mn is dead until the first agg_kernel

    hipMemsetAsync(bcount, 0, (size_t)NBUCK * 4, stream);

    prep_kernel<<<CVT_B + BT_B + BOUNDS_B + COUNT_B, 256, 0, stream>>>(
        x, xb, w1l, w1r, w2l, w2r, w3l, w3r, Bt, batch, gstart, dst, bcount);

    bucket_scan<<<1, 512, 0, stream>>>(bcount, bbase, gcursor, rowptr);
    bucket_scatter<<<COUNT_B, 256, 0, stream>>>(src, dst, gcursor, brec);
    bucket_fill<<<NBUCK, 256, 0, stream>>>(brec, bbase, rowptr, eidx);

    const int AGG_B = (N_NODES + 3) / 4;  // 25000

    agg_kernel<<<AGG_B, 256, 0, stream>>>(xb, rowptr, eidx, mn);
    gemm_kernel<<<GEMM_B, 256, 0, stream>>>(mn, xb, Bt, b1, hA, nullptr, nullptr, nullptr);
    agg_kernel<<<AGG_B, 256, 0, stream>>>(hA, rowptr, eidx, mn);
    gemm_kernel<<<GEMM_B, 256, 0, stream>>>(mn, hA, Bt + 32768, b2, hB, nullptr, nullptr, nullptr);
    agg_kernel<<<AGG_B, 256, 0, stream>>>(hB, rowptr, eidx, mn);
    gemm_kernel<<<GEMM_B, 256, 0, stream>>>(mn, hB, Bt + 65536, b3, hA, gw, gb, gate);

    pool_mlp_kernel<<<NG, 256, 0, stream>>>(hA, gate, gstart, l1w, l1b, l2w, l2b, out);
}